// Round 1
// baseline (148.551 us; speedup 1.0000x reference)
//
#include <hip/hip_runtime.h>
#include <hip/hip_bf16.h>
#include <math.h>

#define C_CH 256

// ---------------------------------------------------------------------------
// Transpose all 4 FPN levels from fp32 (C,H,W) to bf16 (H*W, C) in d_ws.
// R5: one block = full 64-spatial x 256-channel tile (64 KB LDS, 512 thr,
// 1360 blocks). LDS is [sp][ch] with XOR-swizzled 16B column slots
// (q ^= sp>>2): load-phase scalar writes are 2-way (free), store phase is a
// single conflict-free ds_read_b128 per row per lane. Every global store is
// a full contiguous 512 B (H*W,C)-row run -> dense write streams, 4x fewer
// store/LDS-read instructions than the old 64x64 channel-group version.
// 134 MB (89 rd + 45 wr) / 6.3 TB/s roofline = ~21 us.
// ---------------------------------------------------------------------------
__global__ __launch_bounds__(512) void transpose_all(
    const float* __restrict__ f0, const float* __restrict__ f1,
    const float* __restrict__ f2, const float* __restrict__ f3,
    __hip_bfloat16* __restrict__ tf) {
  __shared__ float tile[64 * 256];  // 64 KB, [sp][ch], XOR-swizzled slots
  const int b = blockIdx.x;  // 1360 total
  const float* src;
  int S;
  size_t dstoff;
  int sb;
  if (b < 1024) {        // level0: 1024 sp-tiles
    src = f0; S = 65536; dstoff = 0;     sb = b;
  } else if (b < 1280) { // level1: 256
    src = f1; S = 16384; dstoff = 65536; sb = b - 1024;
  } else if (b < 1344) { // level2: 64
    src = f2; S = 4096;  dstoff = 81920; sb = b - 1280;
  } else {               // level3: 16
    src = f3; S = 1024;  dstoff = 86016; sb = b - 1344;
  }
  const int s0 = sb * 64;

  const int t = threadIdx.x;
  {  // load: float4 along spatial, 256B coalesced runs per channel row
    const int sp4 = (t & 15) * 4;   // 0..60 ; sp>>2 == t&15 for all 4 elems
    const int cb = t >> 4;          // 0..31
    const int K = t & 15;           // swizzle key for these 4 sp rows
    #pragma unroll
    for (int j = 0; j < 8; ++j) {
      const int c = cb + 32 * j;
      const float4 v = *(const float4*)(src + (size_t)c * S + s0 + sp4);
      const int q = (c >> 2) ^ K;   // physical 16B slot
      const int r = c & 3;
      float* p = &tile[sp4 * 256 + q * 4 + r];
      p[0 * 256] = v.x;
      p[1 * 256] = v.y;
      p[2 * 256] = v.z;
      p[3 * 256] = v.w;
    }
  }
  __syncthreads();
  {  // store: ds_read_b128 (conflict-free), full 512B row runs to global
    const int lane = t & 63;
    const int w = t >> 6;  // wave 0..7
    __hip_bfloat16* dst = tf + (dstoff + (size_t)s0) * C_CH;
    #pragma unroll
    for (int j = 0; j < 8; ++j) {
      const int sp = w + 8 * j;
      const int K = (sp >> 2) & 15;
      const float4 v = *(const float4*)&tile[sp * 256 + ((lane ^ K) * 4)];
      union { ushort4 u; __hip_bfloat16 h[4]; } p;
      p.h[0] = __float2bfloat16(v.x);
      p.h[1] = __float2bfloat16(v.y);
      p.h[2] = __float2bfloat16(v.z);
      p.h[3] = __float2bfloat16(v.w);
      *(ushort4*)(dst + (size_t)sp * C_CH + lane * 4) = p.u;
    }
  }
}

__device__ __forceinline__ float bfu(unsigned short s) {
  union { unsigned u; float f; } v;
  v.u = (unsigned)s << 16;
  return v.f;
}

#define OPAD 260  // obuf row stride (floats); %4==0 keeps float4 writes aligned

// ---------------------------------------------------------------------------
// ROI Align + 2x2 max pool, transposed bf16 path. (unchanged this round)
// One 512-thread block (8 waves) per proposal. Waves 0-6 each compute one
// output row oh (all 14 gx, fully unrolled -> deep MLP; lane covers channels
// 4L..4L+3 via ushort4 loads, 512 B/wave/load). Results staged in LDS as
// obuf[p][OPAD] (compute side: 7 conflict-free float4 row writes per lane),
// then one fully-coalesced contiguous 50 KB block store to out.
// ---------------------------------------------------------------------------
__global__ __launch_bounds__(512) void roi_bf16(
    const unsigned short* __restrict__ tf,
    const float* __restrict__ proposals, float* __restrict__ out) {
  __shared__ int xo0[14], xo1[14], yo0[14], yo1[14];
  __shared__ float wxa[14], wxb[14], wya[14], wyb[14];
  __shared__ float obuf[49 * OPAD];

  const int n = blockIdx.x;
  const int t = threadIdx.x;
  const int lane = t & 63;
  const int w = t >> 6;  // wave id 0..7

  const float px1 = proposals[n * 4 + 0];
  const float py1 = proposals[n * 4 + 1];
  const float px2 = proposals[n * 4 + 2];
  const float py2 = proposals[n * 4 + 3];
  float lt = 2.0f + log2f(sqrtf((px2 - px1) * (py2 - py1)) / 224.0f);
  int lvl = (int)floorf(lt);
  lvl = lvl < 0 ? 0 : (lvl > 3 ? 3 : lvl);

  const float scales[4] = {0.25f, 0.125f, 0.0625f, 0.03125f};
  const int sizes[4] = {256, 128, 64, 32};
  const int offs[4] = {0, 65536, 81920, 86016};
  const float sc = scales[lvl];
  const int sz = sizes[lvl];

  const float bx1 = px1 * sc, by1 = py1 * sc;
  const float w_unit = ((px2 - px1) * sc / 7.0f) * 0.5f;
  const float h_unit = ((py2 - py1) * sc / 7.0f) * 0.5f;

  if (t < 14) {
    const int i = t;
    float x = bx1 + ((float)i + 0.5f) * w_unit;
    int xf = (int)floorf(x);
    int x0 = min(max(xf, 0), sz - 1);
    int x1 = min(max(xf + 1, 0), sz - 1);
    wxa[i] = (float)x1 - x;  // matches ref incl. clipped extrapolation
    wxb[i] = x - (float)x0;
    xo0[i] = x0 * C_CH;
    xo1[i] = x1 * C_CH;
  } else if (t >= 64 && t < 78) {
    const int i = t - 64;
    float y = by1 + ((float)i + 0.5f) * h_unit;
    int yf = (int)floorf(y);
    int y0 = min(max(yf, 0), sz - 1);
    int y1 = min(max(yf + 1, 0), sz - 1);
    wya[i] = (float)y1 - y;
    wyb[i] = y - (float)y0;
    yo0[i] = y0 * sz * C_CH;
    yo1[i] = y1 * sz * C_CH;
  }
  __syncthreads();

  if (w < 7) {  // wave-uniform: waves 0-6 compute, wave 7 only helps store
    const int oh = w;
    const int gy0 = 2 * oh, gy1 = 2 * oh + 1;
    const unsigned short* base = tf + (size_t)offs[lvl] * C_CH + lane * 4;
    const unsigned short* r00 = base + yo0[gy0];
    const unsigned short* r01 = base + yo1[gy0];
    const unsigned short* r10 = base + yo0[gy1];
    const unsigned short* r11 = base + yo1[gy1];
    const float wy0a = wya[gy0], wy0b = wyb[gy0];
    const float wy1a = wya[gy1], wy1b = wyb[gy1];

    float mm[7][4];
    #pragma unroll
    for (int j = 0; j < 7; ++j)
      #pragma unroll
      for (int k = 0; k < 4; ++k) mm[j][k] = -INFINITY;

    #pragma unroll
    for (int gx = 0; gx < 14; ++gx) {
      const int xa = xo0[gx], xb = xo1[gx];
      const ushort4 A0 = *(const ushort4*)(r00 + xa);
      const ushort4 A1 = *(const ushort4*)(r00 + xb);
      const ushort4 B0 = *(const ushort4*)(r01 + xa);
      const ushort4 B1 = *(const ushort4*)(r01 + xb);
      const ushort4 C0 = *(const ushort4*)(r10 + xa);
      const ushort4 C1 = *(const ushort4*)(r10 + xb);
      const ushort4 D0 = *(const ushort4*)(r11 + xa);
      const ushort4 D1 = *(const ushort4*)(r11 + xb);
      const float fa = wxa[gx], fb = wxb[gx];
      const int j = gx >> 1;
      const unsigned short* a0 = (const unsigned short*)&A0;
      const unsigned short* a1 = (const unsigned short*)&A1;
      const unsigned short* b0 = (const unsigned short*)&B0;
      const unsigned short* b1 = (const unsigned short*)&B1;
      const unsigned short* c0 = (const unsigned short*)&C0;
      const unsigned short* c1 = (const unsigned short*)&C1;
      const unsigned short* d0 = (const unsigned short*)&D0;
      const unsigned short* d1 = (const unsigned short*)&D1;
      #pragma unroll
      for (int k = 0; k < 4; ++k) {
        const float h00 = fa * bfu(a0[k]) + fb * bfu(a1[k]);
        const float h01 = fa * bfu(b0[k]) + fb * bfu(b1[k]);
        const float va = wy0a * h00 + wy0b * h01;
        const float h10 = fa * bfu(c0[k]) + fb * bfu(c1[k]);
        const float h11 = fa * bfu(d0[k]) + fb * bfu(d1[k]);
        const float vb = wy1a * h10 + wy1b * h11;
        mm[j][k] = fmaxf(mm[j][k], fmaxf(va, vb));
      }
    }

    // Stage: obuf[p][c], p = oh*7+ow. float4 over the 4 channels: the wave
    // writes one contiguous 1 KB row per ow -> conflict-free ds_write_b128.
    #pragma unroll
    for (int ow = 0; ow < 7; ++ow) {
      float4 v = make_float4(mm[ow][0], mm[ow][1], mm[ow][2], mm[ow][3]);
      *(float4*)&obuf[(oh * 7 + ow) * OPAD + lane * 4] = v;
    }
  }
  __syncthreads();

  // Contiguous coalesced block store: out[n*12544 + i], i = c*49 + p.
  float* ob = out + (size_t)n * (C_CH * 49);
  for (int i = t; i < C_CH * 49; i += 512) {
    const unsigned c = (unsigned)i / 49u;
    const unsigned p = (unsigned)i - c * 49u;
    ob[i] = obuf[p * OPAD + c];
  }
}

// ---------------------------------------------------------------------------
// Fallback (no workspace): direct (C,H,W) reads. Correctness-only path.
// ---------------------------------------------------------------------------
__global__ __launch_bounds__(64) void roi_fallback(
    const float* __restrict__ f0, const float* __restrict__ f1,
    const float* __restrict__ f2, const float* __restrict__ f3,
    const float* __restrict__ proposals, float* __restrict__ out) {
  __shared__ int xo0[14], xo1[14], yo0[14], yo1[14];
  __shared__ float wxa[14], wxb[14], wya[14], wyb[14];
  const int n = blockIdx.x;
  const int cblk = blockIdx.y;
  const int lane = threadIdx.x;
  const int c = cblk * 64 + lane;
  const float px1 = proposals[n * 4 + 0];
  const float py1 = proposals[n * 4 + 1];
  const float px2 = proposals[n * 4 + 2];
  const float py2 = proposals[n * 4 + 3];
  float lt = 2.0f + log2f(sqrtf((px2 - px1) * (py2 - py1)) / 224.0f);
  int lvl = (int)floorf(lt);
  lvl = lvl < 0 ? 0 : (lvl > 3 ? 3 : lvl);
  const float scales[4] = {0.25f, 0.125f, 0.0625f, 0.03125f};
  const int sizes[4] = {256, 128, 64, 32};
  const float sc = scales[lvl];
  const int sz = sizes[lvl];
  const float bx1 = px1 * sc, by1 = py1 * sc;
  const float w_unit = ((px2 - px1) * sc / 7.0f) * 0.5f;
  const float h_unit = ((py2 - py1) * sc / 7.0f) * 0.5f;
  if (lane < 14) {
    float x = bx1 + ((float)lane + 0.5f) * w_unit;
    int xf = (int)floorf(x);
    int x0 = min(max(xf, 0), sz - 1);
    int x1 = min(max(xf + 1, 0), sz - 1);
    wxa[lane] = (float)x1 - x;
    wxb[lane] = x - (float)x0;
    xo0[lane] = x0;
    xo1[lane] = x1;
  } else if (lane >= 32 && lane < 46) {
    const int i = lane - 32;
    float y = by1 + ((float)i + 0.5f) * h_unit;
    int yf = (int)floorf(y);
    int y0 = min(max(yf, 0), sz - 1);
    int y1 = min(max(yf + 1, 0), sz - 1);
    wya[i] = (float)y1 - y;
    wyb[i] = y - (float)y0;
    yo0[i] = y0 * sz;
    yo1[i] = y1 * sz;
  }
  __syncthreads();
  const float* fl = (lvl == 0) ? f0 : (lvl == 1) ? f1 : (lvl == 2) ? f2 : f3;
  const float* base = fl + (size_t)c * sz * sz;
  for (int oh = 0; oh < 7; ++oh) {
    float mm[7];
    #pragma unroll
    for (int ow = 0; ow < 7; ++ow) mm[ow] = -INFINITY;
    #pragma unroll
    for (int sy = 0; sy < 2; ++sy) {
      const int gy = oh * 2 + sy;
      const float* r0 = base + yo0[gy];
      const float* r1 = base + yo1[gy];
      const float wy0 = wya[gy], wy1 = wyb[gy];
      #pragma unroll
      for (int gx = 0; gx < 14; ++gx) {
        float v = wy0 * (wxa[gx] * r0[xo0[gx]] + wxb[gx] * r0[xo1[gx]]) +
                  wy1 * (wxa[gx] * r1[xo0[gx]] + wxb[gx] * r1[xo1[gx]]);
        mm[gx >> 1] = fmaxf(mm[gx >> 1], v);
      }
    }
    #pragma unroll
    for (int ow = 0; ow < 7; ++ow)
      out[((size_t)n * C_CH + c) * 49 + oh * 7 + ow] = mm[ow];
  }
}

extern "C" void kernel_launch(void* const* d_in, const int* in_sizes, int n_in,
                              void* d_out, int out_size, void* d_ws,
                              size_t ws_size, hipStream_t stream) {
  const float* f0 = (const float*)d_in[0];
  const float* f1 = (const float*)d_in[1];
  const float* f2 = (const float*)d_in[2];
  const float* f3 = (const float*)d_in[3];
  const float* props = (const float*)d_in[4];
  float* out = (float*)d_out;
  const int N = in_sizes[4] / 4;

  const size_t needed = (size_t)87040 * C_CH * sizeof(__hip_bfloat16);  // 44.6MB
  if (ws_size >= needed) {
    __hip_bfloat16* tf = (__hip_bfloat16*)d_ws;
    transpose_all<<<1360, 512, 0, stream>>>(f0, f1, f2, f3, tf);
    roi_bf16<<<N, 512, 0, stream>>>((const unsigned short*)tf, props, out);
  } else {
    roi_fallback<<<dim3(N, 4), 64, 0, stream>>>(f0, f1, f2, f3, props, out);
  }
}